// Round 9
// baseline (187.392 us; speedup 1.0000x reference)
//
#include <hip/hip_runtime.h>
#include <math.h>

// Single-head causal attention, B=8 T=2048 E=1024 D=64, fp32 in/out.
// wtrans (W -> bf16 W^T) -> qkv (barrier-FREE MFMA GEMM: 1 wave = 16 tokens
// x 192 features, B-frags straight from global x, deep register pipelines)
// -> attn (flash attention, split-K, strip-pairing; unchanged from R8).

#define B_   8
#define T_   2048
#define E_   1024
#define D_   64
#define BT_  (B_ * T_)

typedef __attribute__((ext_vector_type(8))) short s16x8;   // 8 x bf16
typedef __attribute__((ext_vector_type(4))) short s16x4;
typedef __attribute__((ext_vector_type(4))) float f32x4;

__device__ __forceinline__ short f2bf(float f) {
    union { float f; unsigned u; } a; a.f = f;
    unsigned r = a.u + 0x7fffu + ((a.u >> 16) & 1u);   // RNE
    return (short)(r >> 16);
}

#define MFMA16(a, b, c) __builtin_amdgcn_mfma_f32_16x16x32_bf16((a), (b), (c), 0, 0, 0)

// DPP cross-lane move within 16-lane rows (VALU pipe, not DS).
#define DPPF(x, ctrl) __builtin_bit_cast(float, \
    __builtin_amdgcn_update_dpp(0, __builtin_bit_cast(int, (x)), (ctrl), 0xF, 0xF, true))

__device__ __forceinline__ float rsum16(float x) {
    x += DPPF(x, 0xB1);     // quad_perm xor1
    x += DPPF(x, 0x4E);     // quad_perm xor2
    x += DPPF(x, 0x124);    // row_ror:4
    x += DPPF(x, 0x128);    // row_ror:8
    return x;
}

// ---------------------------------------------------------------------------
// Kernel 0: W[1024][64] x3 (fp32) -> Wt[192][1024] (bf16, K-major).
// ---------------------------------------------------------------------------
__global__ __launch_bounds__(256) void wtrans_kernel(
    const float* __restrict__ Wq, const float* __restrict__ Wk,
    const float* __restrict__ Wv, short* __restrict__ Wt)
{
    __shared__ float sT[64][65];
    const int sel = blockIdx.x >> 4;            // 0=q 1=k 2=v
    const int k0  = (blockIdx.x & 15) * 64;
    const float* W = sel == 0 ? Wq : (sel == 1 ? Wk : Wv);
    const int t  = threadIdx.x;
    const int kr = t >> 4, c4 = (t & 15) * 4;
    #pragma unroll
    for (int i = 0; i < 4; ++i) {
        float4 v = *(const float4*)&W[(size_t)(k0 + kr + i * 16) * D_ + c4];
        sT[kr + i * 16][c4 + 0] = v.x; sT[kr + i * 16][c4 + 1] = v.y;
        sT[kr + i * 16][c4 + 2] = v.z; sT[kr + i * 16][c4 + 3] = v.w;
    }
    __syncthreads();
    #pragma unroll
    for (int i = 0; i < 4; ++i) {
        int n  = (t >> 4) + i * 16;
        int kk = (t & 15) * 4;
        s16x4 o;
        o.x = f2bf(sT[kk + 0][n]); o.y = f2bf(sT[kk + 1][n]);
        o.z = f2bf(sT[kk + 2][n]); o.w = f2bf(sT[kk + 3][n]);
        *(s16x4*)&Wt[(size_t)(sel * 64 + n) * E_ + k0 + kk] = o;
    }
}

// ---------------------------------------------------------------------------
// Kernel 1: QKV projection, BARRIER-FREE. Grid 1024 x 64 threads (1 wave).
// Wave owns 16 tokens x 192 features (12 MFMA tiles). B-frags load DIRECTLY
// from global x (lane (l15,quad) reads x[t0+l15][k0+h*32+quad*8..+8) = 32B
// contiguous fp32; 4 lanes cover 128B of a row -> coalesced). x pipelined
// 2 K-steps deep; A-frags (Wt, L2-hot) double-buffered per K-half. With no
// __syncthreads in the loop there is no vmcnt(0) drain -- waves self-pace.
// ---------------------------------------------------------------------------
__global__ __launch_bounds__(64) void qkv_kernel(
    const float* __restrict__ x, const short* __restrict__ Wt,
    const float* __restrict__ bq, const float* __restrict__ bk,
    const float* __restrict__ bv,
    short* __restrict__ Qg, short* __restrict__ Kg, short* __restrict__ VTg)
{
    __shared__ short sVT[64 * 20];              // wave-private V^T staging
    const int lane = threadIdx.x;
    const int l15  = lane & 15, quad = lane >> 4;
    const int t0   = blockIdx.x * 16;
    const int bb   = t0 >> 11;                  // batch (16 | 2048)

    const float* px = &x[(size_t)(t0 + l15) * E_ + quad * 8];
    const short* pw = &Wt[(size_t)l15 * E_ + quad * 8];  // + ft*16*E + k0

    f32x4 acc[12];
    #pragma unroll
    for (int ft = 0; ft < 12; ++ft) acc[ft] = (f32x4){0.f, 0.f, 0.f, 0.f};

    // x pipeline: stage = 4 float4 (frag0: k0+quad*8, frag1: k0+32+quad*8)
    float4 xa[4], xb[4];
    xa[0] = *(const float4*)(px + 0);  xa[1] = *(const float4*)(px + 4);
    xa[2] = *(const float4*)(px + 32); xa[3] = *(const float4*)(px + 36);
    xb[0] = *(const float4*)(px + 64); xb[1] = *(const float4*)(px + 68);
    xb[2] = *(const float4*)(px + 96); xb[3] = *(const float4*)(px + 100);

    // A-frags for k0=0, half 0
    s16x8 aw[12], aw2[12];
    #pragma unroll
    for (int ft = 0; ft < 12; ++ft)
        aw[ft] = *(const s16x8*)(pw + (size_t)ft * 16 * E_);

    for (int k0 = 0; k0 < E_; k0 += 64) {
        // convert this step's B-frags from pipelined registers
        s16x8 b0, b1;
        b0[0] = f2bf(xa[0].x); b0[1] = f2bf(xa[0].y);
        b0[2] = f2bf(xa[0].z); b0[3] = f2bf(xa[0].w);
        b0[4] = f2bf(xa[1].x); b0[5] = f2bf(xa[1].y);
        b0[6] = f2bf(xa[1].z); b0[7] = f2bf(xa[1].w);
        b1[0] = f2bf(xa[2].x); b1[1] = f2bf(xa[2].y);
        b1[2] = f2bf(xa[2].z); b1[3] = f2bf(xa[2].w);
        b1[4] = f2bf(xa[3].x); b1[5] = f2bf(xa[3].y);
        b1[6] = f2bf(xa[3].z); b1[7] = f2bf(xa[3].w);

        // shift x pipeline; issue loads for k0+128 (2 steps ahead)
        #pragma unroll
        for (int i = 0; i < 4; ++i) xa[i] = xb[i];
        if (k0 + 128 < E_) {
            const float* p2 = px + k0 + 128;
            xb[0] = *(const float4*)(p2 + 0);  xb[1] = *(const float4*)(p2 + 4);
            xb[2] = *(const float4*)(p2 + 32); xb[3] = *(const float4*)(p2 + 36);
        }

        // half 0: prefetch A(half1) interleaved with MFMAs on A(half0)
        #pragma unroll
        for (int ft = 0; ft < 12; ++ft) {
            aw2[ft] = *(const s16x8*)(pw + (size_t)ft * 16 * E_ + k0 + 32);
            acc[ft] = MFMA16(aw[ft], b0, acc[ft]);
        }
        // half 1: prefetch A(next k0, half0) interleaved with MFMAs on A(half1)
        const int kn = (k0 + 64 < E_) ? k0 + 64 : k0;
        #pragma unroll
        for (int ft = 0; ft < 12; ++ft) {
            aw[ft] = *(const s16x8*)(pw + (size_t)ft * 16 * E_ + kn);
            acc[ft] = MFMA16(aw2[ft], b1, acc[ft]);
        }
    }

    // ---- epilogue: bias, Q-scale, stores. C: col(l15)=token, row(quad*4+r)
    #pragma unroll
    for (int ft = 0; ft < 12; ++ft) {
        const int fb = (ft & 3) * 16 + quad * 4;
        const float* bias = ft < 4 ? bq : (ft < 8 ? bk : bv);
        f32x4 v = acc[ft] + *(const f32x4*)&bias[fb];
        if (ft < 4) {
            v *= 0.125f;                        // fold 1/sqrt(64) into Q
            s16x4 o = { f2bf(v[0]), f2bf(v[1]), f2bf(v[2]), f2bf(v[3]) };
            *(s16x4*)&Qg[(size_t)(t0 + l15) * D_ + fb] = o;
        } else if (ft < 8) {
            s16x4 o = { f2bf(v[0]), f2bf(v[1]), f2bf(v[2]), f2bf(v[3]) };
            *(s16x4*)&Kg[(size_t)(t0 + l15) * D_ + fb] = o;
        } else {
            #pragma unroll
            for (int r = 0; r < 4; ++r)
                sVT[(fb + r) * 20 + l15] = f2bf(v[r]);
        }
    }
    __syncthreads();                            // single wave: just a waitcnt
    {   // transposed V store: lane = feature d, 16 tokens = 32B contiguous
        const int d = lane;
        s16x8 v0 = *(const s16x8*)&sVT[d * 20];
        s16x8 v1 = *(const s16x8*)&sVT[d * 20 + 8];
        short* pout = &VTg[(size_t)(bb * D_ + d) * T_ + (t0 & (T_ - 1))];
        *(s16x8*)pout = v0;
        *(s16x8*)(pout + 8) = v1;
    }
}

// ---------------------------------------------------------------------------
// Kernel 2: causal flash attention, split-K with strip pairing (R8, passing).
// ---------------------------------------------------------------------------
__global__ __launch_bounds__(256) void attn_kernel(
    const short* __restrict__ Qg, const short* __restrict__ Kg,
    const short* __restrict__ VTg, float* __restrict__ out)
{
    __shared__ char smem[20736];
    short* sP = (short*)smem;                   // [4][16*72] bf16 (loop phase)
    float* sO = (float*)smem;                   // [4][64][20] fp32 (merge, union)
    float* sl = (float*)(smem + 20480);         // [4][16]

    const int tid  = threadIdx.x;
    const int lane = tid & 63;
    const int w    = tid >> 6;
    const int l15  = lane & 15, quad = lane >> 4;
    const int b    = blockIdx.x & 7;
    const int pr   = blockIdx.x >> 3;           // 0..63
    const int jA   = pr, jB = 127 - pr;
    const int tqA  = jA * 16, tqB = jB * 16;
    const int nchA = (jA >> 2) + 1, nchB = (jB >> 2) + 1;
    const int tot  = nchA + nchB;               // 32 or 33
    const int seg  = (tot + 3) >> 2;
    const int c0   = w * seg;
    const int c1   = (c0 + seg < tot) ? c0 + seg : tot;

    const size_t qoffA = ((size_t)b * T_ + tqA + l15) * D_ + quad * 8;
    const s16x8 aqA0 = *(const s16x8*)&Qg[qoffA];      // pre-scaled by 1/8
    const s16x8 aqA1 = *(const s16x8*)&Qg[qoffA + 32];
    const size_t qoffB = ((size_t)b * T_ + tqB + l15) * D_ + quad * 8;
    const s16x8 aqB0 = *(const s16x8*)&Qg[qoffB];
    const s16x8 aqB1 = *(const s16x8*)&Qg[qoffB + 32];

    f32x4 oA[4], oB[4];
    float lA[4] = {0.f, 0.f, 0.f, 0.f}, lB[4] = {0.f, 0.f, 0.f, 0.f};
    #pragma unroll
    for (int nt = 0; nt < 4; ++nt) {
        oA[nt] = (f32x4){0.f, 0.f, 0.f, 0.f};
        oB[nt] = (f32x4){0.f, 0.f, 0.f, 0.f};
    }

    const short* kb = Kg  + (size_t)b * T_ * D_;
    const short* vb = VTg + (size_t)b * D_ * T_;
    short* sPw = sP + w * (16 * 72);

    auto body = [&](int cc, int tq, int nch, const s16x8& q0, const s16x8& q1,
                    f32x4 (&oo)[4], float (&lp)[4]) {
        const int s0 = cc * 64;
        s16x8 bk[4][2];
        #pragma unroll
        for (int nt = 0; nt < 4; ++nt) {
            const short* pk = kb + (size_t)(s0 + nt * 16 + l15) * D_ + quad * 8;
            bk[nt][0] = *(const s16x8*)pk;
            bk[nt][1] = *(const s16x8*)(pk + 32);
        }
        const f32x4 zz = (f32x4){0.f, 0.f, 0.f, 0.f};
        f32x4 sacc[4];
        #pragma unroll
        for (int nt = 0; nt < 4; ++nt) {
            sacc[nt] = MFMA16(q0, bk[nt][0], zz);
            sacc[nt] = MFMA16(q1, bk[nt][1], sacc[nt]);
        }
        s16x8 bv[4][2];
        #pragma unroll
        for (int nt = 0; nt < 4; ++nt) {
            const short* pv = vb + (size_t)(nt * 16 + l15) * T_ + s0 + quad * 8;
            bv[nt][0] = *(const s16x8*)pv;
            bv[nt][1] = *(const s16x8*)(pv + 32);
        }
        const bool diag = (cc == nch - 1);
        float p[4][4];
        #pragma unroll
        for (int nt = 0; nt < 4; ++nt)
            #pragma unroll
            for (int r = 0; r < 4; ++r) {
                float e = __expf(sacc[nt][r]);
                if (diag && (s0 + nt * 16 + l15 > tq + quad * 4 + r)) e = 0.f;
                p[nt][r] = e;
            }
        #pragma unroll
        for (int r = 0; r < 4; ++r)
            lp[r] += (p[0][r] + p[1][r]) + (p[2][r] + p[3][r]);
        #pragma unroll
        for (int nt = 0; nt < 4; ++nt)
            #pragma unroll
            for (int r = 0; r < 4; ++r)
                sPw[(quad * 4 + r) * 72 + nt * 16 + l15] = f2bf(p[nt][r]);
        s16x8 ap0 = *(const s16x8*)&sPw[l15 * 72 + quad * 8];
        s16x8 ap1 = *(const s16x8*)&sPw[l15 * 72 + 32 + quad * 8];
        #pragma unroll
        for (int nt = 0; nt < 4; ++nt) {
            oo[nt] = MFMA16(ap0, bv[nt][0], oo[nt]);
            oo[nt] = MFMA16(ap1, bv[nt][1], oo[nt]);
        }
    };

    for (int c = c0; c < c1; ++c) {
        if (c < nchA) body(c, tqA, nchA, aqA0, aqA1, oA, lA);
        else          body(c - nchA, tqB, nchB, aqB0, aqB1, oB, lB);
    }

    f32x4 lvA, lvB;
    #pragma unroll
    for (int r = 0; r < 4; ++r) { lvA[r] = rsum16(lA[r]); lvB[r] = rsum16(lB[r]); }

    const int d  = tid & 63;
    const int rb = (tid >> 6) * 4;

    // ---- merge strip A
    __syncthreads();                            // all waves done with sP
    {
        float* sOw = sO + w * (64 * 20);
        #pragma unroll
        for (int nt = 0; nt < 4; ++nt)
            *(f32x4*)&sOw[(nt * 16 + l15) * 20 + quad * 4] = oA[nt];
        if (l15 == 0) *(f32x4*)&sl[w * 16 + quad * 4] = lvA;
    }
    __syncthreads();
    {
        f32x4 osum = (f32x4){0.f, 0.f, 0.f, 0.f};
        f32x4 lsum = (f32x4){0.f, 0.f, 0.f, 0.f};
        #pragma unroll
        for (int w2 = 0; w2 < 4; ++w2) {
            osum += *(const f32x4*)&sO[w2 * (64 * 20) + d * 20 + rb];
            lsum += *(const f32x4*)&sl[w2 * 16 + rb];
        }
        #pragma unroll
        for (int i = 0; i < 4; ++i)
            out[((size_t)b * T_ + tqA + rb + i) * D_ + d] = osum[i] / lsum[i];
    }

    // ---- merge strip B
    __syncthreads();
    {
        float* sOw = sO + w * (64 * 20);
        #pragma unroll
        for (int nt = 0; nt < 4; ++nt)
            *(f32x4*)&sOw[(nt * 16 + l15) * 20 + quad * 4] = oB[nt];
        if (l15 == 0) *(f32x4*)&sl[w * 16 + quad * 4] = lvB;
    }
    __syncthreads();
    {
        f32x4 osum = (f32x4){0.f, 0.f, 0.f, 0.f};
        f32x4 lsum = (f32x4){0.f, 0.f, 0.f, 0.f};
        #pragma unroll
        for (int w2 = 0; w2 < 4; ++w2) {
            osum += *(const f32x4*)&sO[w2 * (64 * 20) + d * 20 + rb];
            lsum += *(const f32x4*)&sl[w2 * 16 + rb];
        }
        #pragma unroll
        for (int i = 0; i < 4; ++i)
            out[((size_t)b * T_ + tqB + rb + i) * D_ + d] = osum[i] / lsum[i];
    }
}

extern "C" void kernel_launch(void* const* d_in, const int* in_sizes, int n_in,
                              void* d_out, int out_size, void* d_ws, size_t ws_size,
                              hipStream_t stream) {
    (void)in_sizes; (void)n_in; (void)out_size; (void)ws_size;
    const float* x  = (const float*)d_in[0];
    const float* Wq = (const float*)d_in[1];
    const float* bq = (const float*)d_in[2];
    const float* Wk = (const float*)d_in[3];
    const float* bk = (const float*)d_in[4];
    const float* Wv = (const float*)d_in[5];
    const float* bv = (const float*)d_in[6];

    char* ws = (char*)d_ws;
    short* Qg  = (short*)(ws);                           // [BT][64] bf16, 2 MB
    short* Kg  = (short*)(ws + (size_t)2 * 1024 * 1024);
    short* VTg = (short*)(ws + (size_t)4 * 1024 * 1024); // [B][64][T] bf16
    short* Wt  = (short*)(ws + (size_t)6 * 1024 * 1024); // [192][1024] bf16

    wtrans_kernel<<<48, 256, 0, stream>>>(Wq, Wk, Wv, Wt);
    qkv_kernel<<<BT_ / 16, 64, 0, stream>>>(x, Wt, bq, bk, bv, Qg, Kg, VTg);
    attn_kernel<<<B_ * 64, 256, 0, stream>>>(Qg, Kg, VTg, (float*)d_out);
}

// Round 10
// 161.654 us; speedup vs baseline: 1.1592x; 1.1592x over previous
//
#include <hip/hip_runtime.h>
#include <math.h>

// Single-head causal attention, B=8 T=2048 E=1024 D=64, fp32 in/out.
// wtrans (W -> bf16 W^T) -> qkv (R8 structure: MFMA GEMM, 32 tok/block,
// LDS staging) -> attn (split-K + strip pairing + next-chunk K register
// prefetch, launch_bounds(256,2) so no spills).

#define B_   8
#define T_   2048
#define E_   1024
#define D_   64
#define BT_  (B_ * T_)

typedef __attribute__((ext_vector_type(8))) short s16x8;   // 8 x bf16
typedef __attribute__((ext_vector_type(4))) short s16x4;
typedef __attribute__((ext_vector_type(4))) float f32x4;

__device__ __forceinline__ short f2bf(float f) {
    union { float f; unsigned u; } a; a.f = f;
    unsigned r = a.u + 0x7fffu + ((a.u >> 16) & 1u);   // RNE
    return (short)(r >> 16);
}

#define MFMA16(a, b, c) __builtin_amdgcn_mfma_f32_16x16x32_bf16((a), (b), (c), 0, 0, 0)

// DPP cross-lane move within 16-lane rows (VALU pipe, not DS).
#define DPPF(x, ctrl) __builtin_bit_cast(float, \
    __builtin_amdgcn_update_dpp(0, __builtin_bit_cast(int, (x)), (ctrl), 0xF, 0xF, true))

__device__ __forceinline__ float rsum16(float x) {
    x += DPPF(x, 0xB1);     // quad_perm xor1
    x += DPPF(x, 0x4E);     // quad_perm xor2
    x += DPPF(x, 0x124);    // row_ror:4
    x += DPPF(x, 0x128);    // row_ror:8
    return x;
}

// ---------------------------------------------------------------------------
// Kernel 0: W[1024][64] x3 (fp32) -> Wt[192][1024] (bf16, K-major).
// ---------------------------------------------------------------------------
__global__ __launch_bounds__(256) void wtrans_kernel(
    const float* __restrict__ Wq, const float* __restrict__ Wk,
    const float* __restrict__ Wv, short* __restrict__ Wt)
{
    __shared__ float sT[64][65];
    const int sel = blockIdx.x >> 4;            // 0=q 1=k 2=v
    const int k0  = (blockIdx.x & 15) * 64;
    const float* W = sel == 0 ? Wq : (sel == 1 ? Wk : Wv);
    const int t  = threadIdx.x;
    const int kr = t >> 4, c4 = (t & 15) * 4;
    #pragma unroll
    for (int i = 0; i < 4; ++i) {
        float4 v = *(const float4*)&W[(size_t)(k0 + kr + i * 16) * D_ + c4];
        sT[kr + i * 16][c4 + 0] = v.x; sT[kr + i * 16][c4 + 1] = v.y;
        sT[kr + i * 16][c4 + 2] = v.z; sT[kr + i * 16][c4 + 3] = v.w;
    }
    __syncthreads();
    #pragma unroll
    for (int i = 0; i < 4; ++i) {
        int n  = (t >> 4) + i * 16;
        int kk = (t & 15) * 4;
        s16x4 o;
        o.x = f2bf(sT[kk + 0][n]); o.y = f2bf(sT[kk + 1][n]);
        o.z = f2bf(sT[kk + 2][n]); o.w = f2bf(sT[kk + 3][n]);
        *(s16x4*)&Wt[(size_t)(sel * 64 + n) * E_ + k0 + kk] = o;
    }
}

// ---------------------------------------------------------------------------
// Kernel 1: QKV projection (R8 structure, proven ~40 us).
// ---------------------------------------------------------------------------
__global__ __launch_bounds__(256) void qkv_kernel(
    const float* __restrict__ x, const short* __restrict__ Wt,
    const float* __restrict__ bq, const float* __restrict__ bk,
    const float* __restrict__ bv,
    short* __restrict__ Qg, short* __restrict__ Kg, short* __restrict__ VTg)
{
    __shared__ short sX[2][32 * 76];            // [buf][token][64+12 pad] bf16
    const int tid  = threadIdx.x;
    const int lane = tid & 63;
    const int w    = tid >> 6;
    const int l15  = lane & 15, quad = lane >> 4;
    const int t0   = blockIdx.x * 32;
    const int bb   = t0 >> 11;                  // batch (blocks don't straddle)

    const int srow = tid >> 3;                  // 0..31
    const int skc  = (tid & 7) * 8;             // 0..56
    const float* px = &x[(size_t)(t0 + srow) * E_ + skc];

    f32x4 acc[3][2];
    #pragma unroll
    for (int a = 0; a < 3; ++a)
        #pragma unroll
        for (int h = 0; h < 2; ++h)
            acc[a][h] = (f32x4){0.f, 0.f, 0.f, 0.f};

    float4 lda0 = *(const float4*)px;                 // k0 = 0
    float4 lda1 = *(const float4*)(px + 4);
    float4 ldb0 = *(const float4*)(px + 64);          // k0 = 64
    float4 ldb1 = *(const float4*)(px + 68);

    int buf = 0;
    for (int k0 = 0; k0 < E_; k0 += 64) {
        s16x8 pk;
        pk[0] = f2bf(lda0.x); pk[1] = f2bf(lda0.y);
        pk[2] = f2bf(lda0.z); pk[3] = f2bf(lda0.w);
        pk[4] = f2bf(lda1.x); pk[5] = f2bf(lda1.y);
        pk[6] = f2bf(lda1.z); pk[7] = f2bf(lda1.w);
        *(s16x8*)&sX[buf][srow * 76 + skc] = pk;
        __syncthreads();

        lda0 = ldb0; lda1 = ldb1;               // shift 2-deep pipeline
        if (k0 + 128 < E_) {
            const float* p2 = px + k0 + 128;
            ldb0 = *(const float4*)p2;
            ldb1 = *(const float4*)(p2 + 4);
        }

        s16x8 aw[3][2];
        #pragma unroll
        for (int t3 = 0; t3 < 3; ++t3) {
            const short* pw = &Wt[(size_t)((w * 3 + t3) * 16 + l15) * E_ + k0 + quad * 8];
            aw[t3][0] = *(const s16x8*)pw;
            aw[t3][1] = *(const s16x8*)(pw + 32);
        }
        s16x8 bxf[2][2];
        #pragma unroll
        for (int h = 0; h < 2; ++h) {
            bxf[h][0] = *(const s16x8*)&sX[buf][(h * 16 + l15) * 76 + quad * 8];
            bxf[h][1] = *(const s16x8*)&sX[buf][(h * 16 + l15) * 76 + 32 + quad * 8];
        }
        #pragma unroll
        for (int t3 = 0; t3 < 3; ++t3)
            #pragma unroll
            for (int h = 0; h < 2; ++h) {
                acc[t3][h] = MFMA16(aw[t3][0], bxf[h][0], acc[t3][h]);
                acc[t3][h] = MFMA16(aw[t3][1], bxf[h][1], acc[t3][h]);
            }
        buf ^= 1;
    }

    __syncthreads();                            // main-loop LDS reads done
    short* sVT = &sX[0][0];                     // overlay: [64 feat][48 tok pad]

    #pragma unroll
    for (int t3 = 0; t3 < 3; ++t3) {
        const int nt = w * 3 + t3;
        const int fb = (nt & 3) * 16 + quad * 4;
        const float* bias = nt < 4 ? bq : (nt < 8 ? bk : bv);
        f32x4 bsv = *(const f32x4*)&bias[fb];
        #pragma unroll
        for (int h = 0; h < 2; ++h) {
            const int tok = t0 + h * 16 + l15;
            f32x4 v = acc[t3][h] + bsv;
            if (nt < 4) {
                v *= 0.125f;                    // fold 1/sqrt(64) into Q
                s16x4 o = { f2bf(v[0]), f2bf(v[1]), f2bf(v[2]), f2bf(v[3]) };
                *(s16x4*)&Qg[(size_t)tok * D_ + fb] = o;
            } else if (nt < 8) {
                s16x4 o = { f2bf(v[0]), f2bf(v[1]), f2bf(v[2]), f2bf(v[3]) };
                *(s16x4*)&Kg[(size_t)tok * D_ + fb] = o;
            } else {
                const int lt = h * 16 + l15;
                #pragma unroll
                for (int r = 0; r < 4; ++r)
                    sVT[(fb + r) * 48 + lt] = f2bf(v[r]);
            }
        }
    }
    __syncthreads();
    {   // cooperative transposed V store: 64 features x 32 tokens, 16B/lane
        const int d  = tid >> 2;
        const int tq = (tid & 3) * 8;
        s16x8 vv = *(const s16x8*)&sVT[d * 48 + tq];
        *(s16x8*)&VTg[(size_t)(bb * D_ + d) * T_ + (t0 & (T_ - 1)) + tq] = vv;
    }
}

// ---------------------------------------------------------------------------
// Kernel 2: causal flash attention, split-K + strip pairing + next-chunk K
// register prefetch. No barrier in the K-loop -> prefetch genuinely overlaps.
// launch_bounds(256,2): VGPR cap 256 (fits ~220 est.), 2 blocks/CU.
// ---------------------------------------------------------------------------
__global__ __launch_bounds__(256, 2) void attn_kernel(
    const short* __restrict__ Qg, const short* __restrict__ Kg,
    const short* __restrict__ VTg, float* __restrict__ out)
{
    __shared__ char smem[20736];
    short* sP = (short*)smem;                   // [4][16*72] bf16 (loop phase)
    float* sO = (float*)smem;                   // [4][64][20] fp32 (merge, union)
    float* sl = (float*)(smem + 20480);         // [4][16]

    const int tid  = threadIdx.x;
    const int lane = tid & 63;
    const int w    = tid >> 6;
    const int l15  = lane & 15, quad = lane >> 4;
    const int b    = blockIdx.x & 7;
    const int pr   = blockIdx.x >> 3;           // 0..63
    const int jA   = pr, jB = 127 - pr;
    const int tqA  = jA * 16, tqB = jB * 16;
    const int nchA = (jA >> 2) + 1, nchB = (jB >> 2) + 1;
    const int tot  = nchA + nchB;               // 32 or 33
    const int seg  = (tot + 3) >> 2;
    const int c0   = w * seg;
    const int c1   = (c0 + seg < tot) ? c0 + seg : tot;

    const size_t qoffA = ((size_t)b * T_ + tqA + l15) * D_ + quad * 8;
    const s16x8 aqA0 = *(const s16x8*)&Qg[qoffA];      // pre-scaled by 1/8
    const s16x8 aqA1 = *(const s16x8*)&Qg[qoffA + 32];
    const size_t qoffB = ((size_t)b * T_ + tqB + l15) * D_ + quad * 8;
    const s16x8 aqB0 = *(const s16x8*)&Qg[qoffB];
    const s16x8 aqB1 = *(const s16x8*)&Qg[qoffB + 32];

    f32x4 oA[4], oB[4];
    float lA[4] = {0.f, 0.f, 0.f, 0.f}, lB[4] = {0.f, 0.f, 0.f, 0.f};
    #pragma unroll
    for (int nt = 0; nt < 4; ++nt) {
        oA[nt] = (f32x4){0.f, 0.f, 0.f, 0.f};
        oB[nt] = (f32x4){0.f, 0.f, 0.f, 0.f};
    }

    const short* kb = Kg  + (size_t)b * T_ * D_;
    const short* vb = VTg + (size_t)b * D_ * T_;
    short* sPw = sP + w * (16 * 72);

    // s0 of the c-th chunk in the concatenated A+B list (wave-uniform)
    auto s0_of = [&](int c) {
        return (c < nchA) ? c * 64 : (c - nchA) * 64;
    };

    // preload K frags for chunk c0
    s16x8 kc[4][2];
    {
        const int s0 = s0_of(c0);
        #pragma unroll
        for (int nt = 0; nt < 4; ++nt) {
            const short* pk = kb + (size_t)(s0 + nt * 16 + l15) * D_ + quad * 8;
            kc[nt][0] = *(const s16x8*)pk;
            kc[nt][1] = *(const s16x8*)(pk + 32);
        }
    }

    for (int c = c0; c < c1; ++c) {
        const bool isA = (c < nchA);
        const int cc   = isA ? c : c - nchA;
        const int tq   = isA ? tqA : tqB;
        const int nch  = isA ? nchA : nchB;
        const int s0   = cc * 64;

        // ---- prefetch next chunk's K frags (no barrier in loop -> overlaps)
        s16x8 nk[4][2];
        {
            const int sn = s0_of(c + 1 < c1 ? c + 1 : c);
            #pragma unroll
            for (int nt = 0; nt < 4; ++nt) {
                const short* pk = kb + (size_t)(sn + nt * 16 + l15) * D_ + quad * 8;
                nk[nt][0] = *(const s16x8*)pk;
                nk[nt][1] = *(const s16x8*)(pk + 32);
            }
        }

        // ---- S = Q K^T (current K frags already resident)
        const s16x8 q0 = isA ? aqA0 : aqB0;
        const s16x8 q1 = isA ? aqA1 : aqB1;
        const f32x4 zz = (f32x4){0.f, 0.f, 0.f, 0.f};
        f32x4 sacc[4];
        #pragma unroll
        for (int nt = 0; nt < 4; ++nt) {
            sacc[nt] = MFMA16(q0, kc[nt][0], zz);
            sacc[nt] = MFMA16(q1, kc[nt][1], sacc[nt]);
        }

        // ---- V frags (land during exp + LDS transform)
        s16x8 bv[4][2];
        #pragma unroll
        for (int nt = 0; nt < 4; ++nt) {
            const short* pv = vb + (size_t)(nt * 16 + l15) * T_ + s0 + quad * 8;
            bv[nt][0] = *(const s16x8*)pv;
            bv[nt][1] = *(const s16x8*)(pv + 32);
        }

        // ---- p = exp(s); causal zero on diagonal chunk
        const bool diag = (cc == nch - 1);
        float p[4][4];
        #pragma unroll
        for (int nt = 0; nt < 4; ++nt)
            #pragma unroll
            for (int r = 0; r < 4; ++r) {
                float e = __expf(sacc[nt][r]);
                if (diag && (s0 + nt * 16 + l15 > tq + quad * 4 + r)) e = 0.f;
                p[nt][r] = e;
            }

        // ---- P: C-layout -> LDS -> A-layout (wave-private, no barrier)
        #pragma unroll
        for (int nt = 0; nt < 4; ++nt)
            #pragma unroll
            for (int r = 0; r < 4; ++r)
                sPw[(quad * 4 + r) * 72 + nt * 16 + l15] = f2bf(p[nt][r]);
        s16x8 ap0 = *(const s16x8*)&sPw[l15 * 72 + quad * 8];
        s16x8 ap1 = *(const s16x8*)&sPw[l15 * 72 + 32 + quad * 8];

        // ---- accumulate (wave-uniform branch; no divergence)
        if (isA) {
            #pragma unroll
            for (int r = 0; r < 4; ++r)
                lA[r] += (p[0][r] + p[1][r]) + (p[2][r] + p[3][r]);
            #pragma unroll
            for (int nt = 0; nt < 4; ++nt) {
                oA[nt] = MFMA16(ap0, bv[nt][0], oA[nt]);
                oA[nt] = MFMA16(ap1, bv[nt][1], oA[nt]);
            }
        } else {
            #pragma unroll
            for (int r = 0; r < 4; ++r)
                lB[r] += (p[0][r] + p[1][r]) + (p[2][r] + p[3][r]);
            #pragma unroll
            for (int nt = 0; nt < 4; ++nt) {
                oB[nt] = MFMA16(ap0, bv[nt][0], oB[nt]);
                oB[nt] = MFMA16(ap1, bv[nt][1], oB[nt]);
            }
        }

        #pragma unroll
        for (int nt = 0; nt < 4; ++nt) {
            kc[nt][0] = nk[nt][0]; kc[nt][1] = nk[nt][1];
        }
    }

    f32x4 lvA, lvB;
    #pragma unroll
    for (int r = 0; r < 4; ++r) { lvA[r] = rsum16(lA[r]); lvB[r] = rsum16(lB[r]); }

    const int d  = tid & 63;
    const int rb = (tid >> 6) * 4;

    // ---- merge strip A
    __syncthreads();                            // all waves done with sP
    {
        float* sOw = sO + w * (64 * 20);
        #pragma unroll
        for (int nt = 0; nt < 4; ++nt)
            *(f32x4*)&sOw[(nt * 16 + l15) * 20 + quad * 4] = oA[nt];
        if (l15 == 0) *(f32x4*)&sl[w * 16 + quad * 4] = lvA;
    }
    __syncthreads();
    {
        f32x4 osum = (f32x4){0.f, 0.f, 0.f, 0.f};
        f32x4 lsum = (f32x4){0.f, 0.f, 0.f, 0.f};
        #pragma unroll
        for (int w2 = 0; w2 < 4; ++w2) {
            osum += *(const f32x4*)&sO[w2 * (64 * 20) + d * 20 + rb];
            lsum += *(const f32x4*)&sl[w2 * 16 + rb];
        }
        #pragma unroll
        for (int i = 0; i < 4; ++i)
            out[((size_t)b * T_ + tqA + rb + i) * D_ + d] = osum[i] / lsum[i];
    }

    // ---- merge strip B
    __syncthreads();
    {
        float* sOw = sO + w * (64 * 20);
        #pragma unroll
        for (int nt = 0; nt < 4; ++nt)
            *(f32x4*)&sOw[(nt * 16 + l15) * 20 + quad * 4] = oB[nt];
        if (l15 == 0) *(f32x4*)&sl[w * 16 + quad * 4] = lvB;
    }
    __syncthreads();
    {
        f32x4 osum = (f32x4){0.f, 0.f, 0.f, 0.f};
        f32x4 lsum = (f32x4){0.f, 0.f, 0.f, 0.f};
        #pragma unroll
        for (int w2 = 0; w2 < 4; ++w2) {
            osum += *(const f32x4*)&sO[w2 * (64 * 20) + d * 20 + rb];
            lsum += *(const f32x4*)&sl[w2 * 16 + rb];
        }
        #pragma unroll
        for (int i = 0; i < 4; ++i)
            out[((size_t)b * T_ + tqB + rb + i) * D_ + d] = osum[i] / lsum[i];
    }
}

extern "C" void kernel_launch(void* const* d_in, const int* in_sizes, int n_in,
                              void* d_out, int out_size, void* d_ws, size_t ws_size,
                              hipStream_t stream) {
    (void)in_sizes; (void)n_in; (void)out_size; (void)ws_size;
    const float* x  = (const float*)d_in[0];
    const float* Wq = (const float*)d_in[1];
    const float* bq = (const float*)d_in[2];
    const float* Wk = (const float*)d_in[3];
    const float* bk = (const float*)d_in[4];
    const float* Wv = (const float*)d_in[5];
    const float* bv = (const float*)d_in[6];

    char* ws = (char*)d_ws;
    short* Qg  = (short*)(ws);                           // [BT][64] bf16, 2 MB
    short* Kg  = (short*)(ws + (size_t)2 * 1024 * 1024);
    short* VTg = (short*)(ws + (size_t)4 * 1024 * 1024); // [B][64][T] bf16
    short* Wt  = (short*)(ws + (size_t)6 * 1024 * 1024); // [192][1024] bf16

    wtrans_kernel<<<48, 256, 0, stream>>>(Wq, Wk, Wv, Wt);
    qkv_kernel<<<BT_ / 32, 256, 0, stream>>>(x, Wt, bq, bk, bv, Qg, Kg, VTg);
    attn_kernel<<<B_ * 64, 256, 0, stream>>>(Qg, Kg, VTg, (float*)d_out);
}